// Round 8
// baseline (626.964 us; speedup 1.0000x reference)
//
#include <hip/hip_runtime.h>
#include <hip/hip_fp16.h>

#define N_NODES 100000
#define N_EDGESV 1000000
#define N_REL 7
#define IN_CH 128
#define HID_CH 64
#define OUT_CH 2
#define NB 4
#define DI 32
#define DO 16
#define NBINS 800000          // (dst, rel) bins: key = d*8 + r
#define SCAN_CHUNK 1024
#define NCHUNK2 ((NBINS + SCAN_CHUNK - 1) / SCAN_CHUNK)  // 782
#define NEGI -3.0e38f

// ================= CSR build over (dst, rel) keys =================
__global__ void hist_kernel(const int* __restrict__ ei, const int* __restrict__ et,
                            int* __restrict__ deg2) {
    int e = blockIdx.x * blockDim.x + threadIdx.x;
    if (e < N_EDGESV) atomicAdd(&deg2[(ei[N_EDGESV + e] << 3) + et[e]], 1);
}

__global__ void scan1_kernel(const int* __restrict__ deg2, int* __restrict__ off2,
                             int* __restrict__ sums) {
    __shared__ int lds[256];
    const int tid = threadIdx.x;
    const int base = blockIdx.x * SCAN_CHUNK + tid * 4;
    int v0 = (base + 0 < NBINS) ? deg2[base + 0] : 0;
    int v1 = (base + 1 < NBINS) ? deg2[base + 1] : 0;
    int v2 = (base + 2 < NBINS) ? deg2[base + 2] : 0;
    int v3 = (base + 3 < NBINS) ? deg2[base + 3] : 0;
    int t0 = v0, t1 = v0 + v1, t2 = t1 + v2, t3 = t2 + v3;
    lds[tid] = t3;
    __syncthreads();
    for (int d = 1; d < 256; d <<= 1) {
        int t = (tid >= d) ? lds[tid - d] : 0;
        __syncthreads();
        if (tid >= d) lds[tid] += t;
        __syncthreads();
    }
    int excl = lds[tid] - t3;
    if (base + 0 < NBINS) off2[base + 1] = excl + t0;
    if (base + 1 < NBINS) off2[base + 2] = excl + t1;
    if (base + 2 < NBINS) off2[base + 3] = excl + t2;
    if (base + 3 < NBINS) off2[base + 4] = excl + t3;
    if (tid == 255) sums[blockIdx.x] = lds[255];
}

__global__ void scan2_kernel(int* __restrict__ sums) {
    __shared__ int lds[1024];
    int t = threadIdx.x;
    lds[t] = (t < NCHUNK2) ? sums[t] : 0;
    __syncthreads();
    for (int d = 1; d < 1024; d <<= 1) {
        int v = (t >= d) ? lds[t - d] : 0;
        __syncthreads();
        if (t >= d) lds[t] += v;
        __syncthreads();
    }
    if (t < NCHUNK2) sums[t] = lds[t];
}

__global__ void scan3_kernel(int* __restrict__ off2, const int* __restrict__ sums,
                             int* __restrict__ cursor2) {
    int i = blockIdx.x * blockDim.x + threadIdx.x;
    if (i == 0) { off2[0] = 0; cursor2[0] = 0; }
    if (i < NBINS) {
        int chunk = i / SCAN_CHUNK;
        int v = off2[i + 1] + ((chunk > 0) ? sums[chunk - 1] : 0);
        off2[i + 1] = v;
        cursor2[i + 1] = v;
    }
}

// packed1: byte offset into msg1 = s*896 + r*128 (r implied by segment)
// packed2: byte offset into msg2 = s*64 + r*8
__global__ void scatter_kernel(const int* __restrict__ ei, const int* __restrict__ et,
                               int* __restrict__ cursor2, int* __restrict__ packed1,
                               int* __restrict__ packed2) {
    int e = blockIdx.x * blockDim.x + threadIdx.x;
    if (e < N_EDGESV) {
        int d = ei[N_EDGESV + e];
        int s = ei[e];
        int r = et[e];
        int pos = atomicAdd(&cursor2[(d << 3) + r], 1);
        packed1[pos] = s * 896 + r * 128;
        packed2[pos] = s * 64 + r * 8;
    }
}

// ========== rootmm: K-split halves, Q COMPILE-TIME (keeps w[] in VGPRs), 4-node ILP ==========
// hrootp[q][n][c] = x[n][64q:64q+64] @ root1[64q:64q+64, :]
template<int Q>
__global__ __launch_bounds__(256)
void rootmm_kernel(const float* __restrict__ x, const float* __restrict__ root1,
                   float* __restrict__ hrootp)
{
    const int lane = threadIdx.x & 63;  // output channel
    float w[64];
#pragma unroll
    for (int i = 0; i < 64; ++i) w[i] = root1[(Q * 64 + i) * HID_CH + lane];  // static idx

    float* hp = hrootp + (size_t)Q * N_NODES * HID_CH;
    const int wid = blockIdx.x * 4 + (threadIdx.x >> 6);
    const int nw = gridDim.x * 4;
    const int NQ = N_NODES / 4;  // 25000

    for (int g = wid; g < NQ; g += nw) {
        const int n0 = g * 4;
        const float4* xr0 = (const float4*)(x + (size_t)(n0 + 0) * IN_CH + Q * 64);
        const float4* xr1 = (const float4*)(x + (size_t)(n0 + 1) * IN_CH + Q * 64);
        const float4* xr2 = (const float4*)(x + (size_t)(n0 + 2) * IN_CH + Q * 64);
        const float4* xr3 = (const float4*)(x + (size_t)(n0 + 3) * IN_CH + Q * 64);
        float a0 = 0.f, a1 = 0.f, a2 = 0.f, a3 = 0.f;
#pragma unroll
        for (int i4 = 0; i4 < 16; ++i4) {
            float4 p = xr0[i4];  // 4 independent broadcast loads / iter
            float4 q = xr1[i4];
            float4 r = xr2[i4];
            float4 s = xr3[i4];
            a0 = fmaf(p.x, w[i4 * 4 + 0], a0); a0 = fmaf(p.y, w[i4 * 4 + 1], a0);
            a0 = fmaf(p.z, w[i4 * 4 + 2], a0); a0 = fmaf(p.w, w[i4 * 4 + 3], a0);
            a1 = fmaf(q.x, w[i4 * 4 + 0], a1); a1 = fmaf(q.y, w[i4 * 4 + 1], a1);
            a1 = fmaf(q.z, w[i4 * 4 + 2], a1); a1 = fmaf(q.w, w[i4 * 4 + 3], a1);
            a2 = fmaf(r.x, w[i4 * 4 + 0], a2); a2 = fmaf(r.y, w[i4 * 4 + 1], a2);
            a2 = fmaf(r.z, w[i4 * 4 + 2], a2); a2 = fmaf(r.w, w[i4 * 4 + 3], a2);
            a3 = fmaf(s.x, w[i4 * 4 + 0], a3); a3 = fmaf(s.y, w[i4 * 4 + 1], a3);
            a3 = fmaf(s.z, w[i4 * 4 + 2], a3); a3 = fmaf(s.w, w[i4 * 4 + 3], a3);
        }
        hp[(size_t)(n0 + 0) * HID_CH + lane] = a0;
        hp[(size_t)(n0 + 1) * HID_CH + lane] = a1;
        hp[(size_t)(n0 + 2) * HID_CH + lane] = a2;
        hp[(size_t)(n0 + 3) * HID_CH + lane] = a3;
    }
}

// ========== pre1: msg1[n][r][c] fp16; COMPILE-TIME NR (no scratch spill) ==========
template<int RBASE, int NR>
__device__ __forceinline__ void pre1_work(const float* __restrict__ x,
                                          const float* __restrict__ W1,
                                          __half* __restrict__ msg1,
                                          int wid, int nw)
{
    const int lane = threadIdx.x & 63;
    const int b = lane >> 4;
    const int j = lane & 15;

    float w[NR][DI];  // static indices after full unroll -> real VGPRs
#pragma unroll
    for (int rr = 0; rr < NR; ++rr) {
        const float* wp = W1 + ((size_t)((RBASE + rr) * NB + b) * DI) * DO + j;
#pragma unroll
        for (int i = 0; i < DI; ++i) w[rr][i] = wp[i * DO];
    }

    const int NPAIR = N_NODES / 2;
    for (int np = wid; np < NPAIR; np += nw) {
        const int n0 = np * 2;
        const float4* xr0 = (const float4*)(x + ((size_t)n0 << 7)) + (b << 3);
        const float4* xr1 = xr0 + 32;
        float4 xa[8], xb[8];
#pragma unroll
        for (int i4 = 0; i4 < 8; ++i4) { xa[i4] = xr0[i4]; xb[i4] = xr1[i4]; }
        __half* m0 = msg1 + (size_t)n0 * (N_REL * HID_CH) + (RBASE << 6) + lane;
        __half* m1 = m0 + N_REL * HID_CH;
#pragma unroll
        for (int rr = 0; rr < NR; ++rr) {
            float s0 = 0.f, s1 = 0.f;
#pragma unroll
            for (int i4 = 0; i4 < 8; ++i4) {
                s0 = fmaf(xa[i4].x, w[rr][i4 * 4 + 0], s0);
                s0 = fmaf(xa[i4].y, w[rr][i4 * 4 + 1], s0);
                s0 = fmaf(xa[i4].z, w[rr][i4 * 4 + 2], s0);
                s0 = fmaf(xa[i4].w, w[rr][i4 * 4 + 3], s0);
                s1 = fmaf(xb[i4].x, w[rr][i4 * 4 + 0], s1);
                s1 = fmaf(xb[i4].y, w[rr][i4 * 4 + 1], s1);
                s1 = fmaf(xb[i4].z, w[rr][i4 * 4 + 2], s1);
                s1 = fmaf(xb[i4].w, w[rr][i4 * 4 + 3], s1);
            }
            m0[rr << 6] = __float2half(s0);
            m1[rr << 6] = __float2half(s1);
        }
    }
}

__global__ __launch_bounds__(256)
void pre1_kernel(const float* __restrict__ x, const float* __restrict__ W1,
                 __half* __restrict__ msg1)
{
    const int grp = blockIdx.x & 3;
    const int wid = (blockIdx.x >> 2) * 4 + (threadIdx.x >> 6);
    const int nw = (gridDim.x >> 2) * 4;
    if (grp == 0)      pre1_work<0, 2>(x, W1, msg1, wid, nw);
    else if (grp == 1) pre1_work<2, 2>(x, W1, msg1, wid, nw);
    else if (grp == 2) pre1_work<4, 2>(x, W1, msg1, wid, nw);
    else               pre1_work<6, 1>(x, W1, msg1, wid, nw);
}

// ========== agg1: wave/node; 7 contiguous (dst,rel) segments; h = relu(root+bias+sum max) ==========
__global__ __launch_bounds__(256)
void agg1_kernel(const __half* __restrict__ msg1, const float* __restrict__ hrootp,
                 const float* __restrict__ bias1, const int* __restrict__ off2,
                 const int* __restrict__ packed1, float* __restrict__ h)
{
    const int lane = threadIdx.x & 63;
    const int lane2 = lane * 2;
    const char* m1 = (const char*)msg1;
    const int wid = blockIdx.x * 4 + (threadIdx.x >> 6);
    const int nw = gridDim.x * 4;
    const float bias = bias1[lane];

    for (int n = wid; n < N_NODES; n += nw) {
        const int4* ob = (const int4*)(off2 + (n << 3));
        const int4 oa = ob[0];   // v0..v3
        const int4 oc = ob[1];   // v4..v7
        float add = 0.f;

#define SEG1(st_, en_) { \
        const int st = st_, en = en_; \
        float m = NEGI; \
        int p = st; \
        for (; p + 1 < en; p += 2) { \
            int k0 = packed1[p], k1 = packed1[p + 1]; \
            float v0 = __half2float(*(const __half*)(m1 + (k0 + lane2))); \
            float v1 = __half2float(*(const __half*)(m1 + (k1 + lane2))); \
            m = fmaxf(m, fmaxf(v0, v1)); \
        } \
        if (p < en) { \
            int k0 = packed1[p]; \
            m = fmaxf(m, __half2float(*(const __half*)(m1 + (k0 + lane2)))); \
        } \
        if (en > st) add += m; }

        SEG1(oa.x, oa.y) SEG1(oa.y, oa.z) SEG1(oa.z, oa.w) SEG1(oa.w, oc.x)
        SEG1(oc.x, oc.y) SEG1(oc.y, oc.z) SEG1(oc.z, oc.w)
#undef SEG1

        const size_t hi = ((size_t)n << 6) + lane;
        float v = hrootp[hi] + hrootp[(size_t)N_NODES * HID_CH + hi] + bias + add;
        h[hi] = fmaxf(v, 0.f);
    }
}

// ========== pre2: msg2[n][16] = [h@W2[0..6] (2 each), h@root2+bias2 (2)] ==========
__global__ __launch_bounds__(256)
void pre2_kernel(const float* __restrict__ h, const float* __restrict__ comp2,
                 const float* __restrict__ basis2, const float* __restrict__ root2,
                 const float* __restrict__ bias2, float* __restrict__ msg2)
{
    const int lane = threadIdx.x & 63;
    const int sub = lane >> 4;   // node within quad
    const int o = lane & 15;     // output column 0..15

    float w[64];
    if (o < 14) {
        const int r = o >> 1, oc = o & 1;
        float c0 = comp2[r * NB + 0], c1 = comp2[r * NB + 1];
        float c2 = comp2[r * NB + 2], c3 = comp2[r * NB + 3];
#pragma unroll
        for (int i = 0; i < 64; ++i) {
            w[i] = c0 * basis2[(0 * HID_CH + i) * OUT_CH + oc]
                 + c1 * basis2[(1 * HID_CH + i) * OUT_CH + oc]
                 + c2 * basis2[(2 * HID_CH + i) * OUT_CH + oc]
                 + c3 * basis2[(3 * HID_CH + i) * OUT_CH + oc];
        }
    } else {
        const int oc = o - 14;
#pragma unroll
        for (int i = 0; i < 64; ++i) w[i] = root2[i * OUT_CH + oc];
    }
    const float badd = (o == 14) ? bias2[0] : ((o == 15) ? bias2[1] : 0.f);

    const int wid = blockIdx.x * 4 + (threadIdx.x >> 6);
    const int nw = gridDim.x * 4;
    const int NQUAD = N_NODES / 4;

    for (int nq = wid; nq < NQUAD; nq += nw) {
        const int n = nq * 4 + sub;
        const float4* hr = (const float4*)(h + ((size_t)n << 6));
        float acc = badd;
#pragma unroll
        for (int i4 = 0; i4 < 16; ++i4) {
            float4 hv = hr[i4];
            acc = fmaf(hv.x, w[i4 * 4 + 0], acc);
            acc = fmaf(hv.y, w[i4 * 4 + 1], acc);
            acc = fmaf(hv.z, w[i4 * 4 + 2], acc);
            acc = fmaf(hv.w, w[i4 * 4 + 3], acc);
        }
        msg2[(size_t)nq * 64 + lane] = acc;  // == msg2[n*16 + o], 256B/wave
    }
}

// ========== agg2: thread/node; 7 segments of float2 gathers ==========
__global__ __launch_bounds__(256)
void agg2_kernel(const float* __restrict__ msg2, const int* __restrict__ off2,
                 const int* __restrict__ packed2, float* __restrict__ out)
{
    const int n = blockIdx.x * blockDim.x + threadIdx.x;
    if (n >= N_NODES) return;
    const char* m2 = (const char*)msg2;
    const int4* ob = (const int4*)(off2 + (n << 3));
    const int4 oa = ob[0];
    const int4 oc = ob[1];
    float o0 = msg2[(size_t)n * 16 + 14];  // self + bias pre-folded
    float o1 = msg2[(size_t)n * 16 + 15];

#define SEG2(st_, en_) { \
    const int st = st_, en = en_; \
    float mx = NEGI, my = NEGI; \
    for (int p = st; p < en; ++p) { \
        const float2 f = *(const float2*)(m2 + packed2[p]); \
        mx = fmaxf(mx, f.x); \
        my = fmaxf(my, f.y); \
    } \
    if (en > st) { o0 += mx; o1 += my; } }

    SEG2(oa.x, oa.y) SEG2(oa.y, oa.z) SEG2(oa.z, oa.w) SEG2(oa.w, oc.x)
    SEG2(oc.x, oc.y) SEG2(oc.y, oc.z) SEG2(oc.z, oc.w)
#undef SEG2

    out[(size_t)n * OUT_CH + 0] = o0;
    out[(size_t)n * OUT_CH + 1] = o1;
}

extern "C" void kernel_launch(void* const* d_in, const int* in_sizes, int n_in,
                              void* d_out, int out_size, void* d_ws, size_t ws_size,
                              hipStream_t stream)
{
    const float* x      = (const float*)d_in[0];
    const int*   ei     = (const int*)d_in[1];
    const int*   et     = (const int*)d_in[2];
    const float* W1     = (const float*)d_in[3];
    const float* root1  = (const float*)d_in[4];
    const float* bias1  = (const float*)d_in[5];
    const float* comp2  = (const float*)d_in[6];
    const float* basis2 = (const float*)d_in[7];
    const float* root2  = (const float*)d_in[8];
    const float* bias2  = (const float*)d_in[9];
    float* out = (float*)d_out;

    // workspace carve-up (~191 MB)
    char* ws = (char*)d_ws;
    size_t o = 0;
    auto carve = [&](size_t bytes) { char* p = ws + o; o += (bytes + 255) & ~(size_t)255; return p; };
    int*    deg2    = (int*)carve(sizeof(int) * NBINS);
    int*    off2    = (int*)carve(sizeof(int) * (NBINS + 1));
    int*    cursor2 = (int*)carve(sizeof(int) * (NBINS + 1));
    int*    sums    = (int*)carve(sizeof(int) * 1024);
    int*    packed1 = (int*)carve(sizeof(int) * N_EDGESV);
    int*    packed2 = (int*)carve(sizeof(int) * N_EDGESV);
    __half* msg1    = (__half*)carve(sizeof(__half) * (size_t)N_NODES * N_REL * HID_CH);  // 89.6 MB
    float*  hrootp  = (float*)carve(sizeof(float) * 2 * (size_t)N_NODES * HID_CH);        // 51.2 MB
    float*  h       = (float*)carve(sizeof(float) * (size_t)N_NODES * HID_CH);            // 25.6 MB
    float*  msg2    = (float*)carve(sizeof(float) * (size_t)N_NODES * 16);                //  6.4 MB

    // ---- CSR build over (dst, rel) ----
    hipMemsetAsync(deg2, 0, sizeof(int) * NBINS, stream);
    hist_kernel<<<(N_EDGESV + 255) / 256, 256, 0, stream>>>(ei, et, deg2);
    scan1_kernel<<<NCHUNK2, 256, 0, stream>>>(deg2, off2, sums);
    scan2_kernel<<<1, 1024, 0, stream>>>(sums);
    scan3_kernel<<<(NBINS + 255) / 256, 256, 0, stream>>>(off2, sums, cursor2);
    scatter_kernel<<<(N_EDGESV + 255) / 256, 256, 0, stream>>>(ei, et, cursor2, packed1, packed2);

    // ---- dense precomputes (compile-time static weight indices -> VGPRs) ----
    rootmm_kernel<0><<<512, 256, 0, stream>>>(x, root1, hrootp);
    rootmm_kernel<1><<<512, 256, 0, stream>>>(x, root1, hrootp);
    pre1_kernel<<<2048, 256, 0, stream>>>(x, W1, msg1);

    // ---- layer 1 aggregation ----
    agg1_kernel<<<2048, 256, 0, stream>>>(msg1, hrootp, bias1, off2, packed1, h);

    // ---- layer 2 dense messages + aggregation ----
    pre2_kernel<<<1024, 256, 0, stream>>>(h, comp2, basis2, root2, bias2, msg2);
    agg2_kernel<<<(N_NODES + 255) / 256, 256, 0, stream>>>(msg2, off2, packed2, out);
}

// Round 9
// 536.752 us; speedup vs baseline: 1.1681x; 1.1681x over previous
//
#include <hip/hip_runtime.h>
#include <hip/hip_fp16.h>

#define N_NODES 100000
#define N_EDGESV 1000000
#define N_REL 7
#define IN_CH 128
#define HID_CH 64
#define OUT_CH 2
#define NB 4
#define DI 32
#define DO 16
#define NBINS 800000          // (dst, rel) bins: key = d*8 + r
#define SCAN_CHUNK 1024
#define NCHUNK2 ((NBINS + SCAN_CHUNK - 1) / SCAN_CHUNK)  // 782
#define OFFM 0x0FFFFFFFu

// ================= CSR build over (dst, rel) keys =================
__global__ void hist_kernel(const int* __restrict__ ei, const int* __restrict__ et,
                            int* __restrict__ deg2) {
    int e = blockIdx.x * blockDim.x + threadIdx.x;
    if (e < N_EDGESV) atomicAdd(&deg2[(ei[N_EDGESV + e] << 3) + et[e]], 1);
}

__global__ void scan1_kernel(const int* __restrict__ deg2, int* __restrict__ off2,
                             int* __restrict__ sums) {
    __shared__ int lds[256];
    const int tid = threadIdx.x;
    const int base = blockIdx.x * SCAN_CHUNK + tid * 4;
    int v0 = (base + 0 < NBINS) ? deg2[base + 0] : 0;
    int v1 = (base + 1 < NBINS) ? deg2[base + 1] : 0;
    int v2 = (base + 2 < NBINS) ? deg2[base + 2] : 0;
    int v3 = (base + 3 < NBINS) ? deg2[base + 3] : 0;
    int t0 = v0, t1 = v0 + v1, t2 = t1 + v2, t3 = t2 + v3;
    lds[tid] = t3;
    __syncthreads();
    for (int d = 1; d < 256; d <<= 1) {
        int t = (tid >= d) ? lds[tid - d] : 0;
        __syncthreads();
        if (tid >= d) lds[tid] += t;
        __syncthreads();
    }
    int excl = lds[tid] - t3;
    if (base + 0 < NBINS) off2[base + 1] = excl + t0;
    if (base + 1 < NBINS) off2[base + 2] = excl + t1;
    if (base + 2 < NBINS) off2[base + 3] = excl + t2;
    if (base + 3 < NBINS) off2[base + 4] = excl + t3;
    if (tid == 255) sums[blockIdx.x] = lds[255];
}

__global__ void scan2_kernel(int* __restrict__ sums) {
    __shared__ int lds[1024];
    int t = threadIdx.x;
    lds[t] = (t < NCHUNK2) ? sums[t] : 0;
    __syncthreads();
    for (int d = 1; d < 1024; d <<= 1) {
        int v = (t >= d) ? lds[t - d] : 0;
        __syncthreads();
        if (t >= d) lds[t] += v;
        __syncthreads();
    }
    if (t < NCHUNK2) sums[t] = lds[t];
}

__global__ void scan3_kernel(int* __restrict__ off2, const int* __restrict__ sums,
                             int* __restrict__ cursor2) {
    int i = blockIdx.x * blockDim.x + threadIdx.x;
    if (i == 0) { off2[0] = 0; cursor2[0] = 0; }
    if (i < NBINS) {
        int chunk = i / SCAN_CHUNK;
        int v = off2[i + 1] + ((chunk > 0) ? sums[chunk - 1] : 0);
        off2[i + 1] = v;
        cursor2[i + 1] = v;
    }
}

// packed1: (byte offset into msg1 = s*896 + r*128) | r<<28   (off < 2^27)
// packed2: byte offset into msg2 = s*64 + r*8 ; r = (pk>>3)&7
__global__ void scatter_kernel(const int* __restrict__ ei, const int* __restrict__ et,
                               int* __restrict__ cursor2, int* __restrict__ packed1,
                               int* __restrict__ packed2) {
    int e = blockIdx.x * blockDim.x + threadIdx.x;
    if (e < N_EDGESV) {
        int d = ei[N_EDGESV + e];
        int s = ei[e];
        int r = et[e];
        int pos = atomicAdd(&cursor2[(d << 3) + r], 1);
        packed1[pos] = (s * 896 + r * 128) | (r << 28);
        packed2[pos] = s * 64 + r * 8;
    }
}

// ========== rootmm: K-split halves, Q compile-time, 4-node ILP, VGPR budget 256 ==========
template<int Q>
__global__ __launch_bounds__(256, 2)
void rootmm_kernel(const float* __restrict__ x, const float* __restrict__ root1,
                   float* __restrict__ hrootp)
{
    const int lane = threadIdx.x & 63;
    float w[64];
#pragma unroll
    for (int i = 0; i < 64; ++i) w[i] = root1[(Q * 64 + i) * HID_CH + lane];

    float* hp = hrootp + (size_t)Q * N_NODES * HID_CH;
    const int wid = blockIdx.x * 4 + (threadIdx.x >> 6);
    const int nw = gridDim.x * 4;
    const int NQ = N_NODES / 4;

    for (int g = wid; g < NQ; g += nw) {
        const int n0 = g * 4;
        const float4* xr0 = (const float4*)(x + (size_t)(n0 + 0) * IN_CH + Q * 64);
        const float4* xr1 = (const float4*)(x + (size_t)(n0 + 1) * IN_CH + Q * 64);
        const float4* xr2 = (const float4*)(x + (size_t)(n0 + 2) * IN_CH + Q * 64);
        const float4* xr3 = (const float4*)(x + (size_t)(n0 + 3) * IN_CH + Q * 64);
        float a0 = 0.f, a1 = 0.f, a2 = 0.f, a3 = 0.f;
#pragma unroll
        for (int i4 = 0; i4 < 16; ++i4) {
            float4 p = xr0[i4];
            float4 q = xr1[i4];
            float4 r = xr2[i4];
            float4 s = xr3[i4];
            a0 = fmaf(p.x, w[i4 * 4 + 0], a0); a0 = fmaf(p.y, w[i4 * 4 + 1], a0);
            a0 = fmaf(p.z, w[i4 * 4 + 2], a0); a0 = fmaf(p.w, w[i4 * 4 + 3], a0);
            a1 = fmaf(q.x, w[i4 * 4 + 0], a1); a1 = fmaf(q.y, w[i4 * 4 + 1], a1);
            a1 = fmaf(q.z, w[i4 * 4 + 2], a1); a1 = fmaf(q.w, w[i4 * 4 + 3], a1);
            a2 = fmaf(r.x, w[i4 * 4 + 0], a2); a2 = fmaf(r.y, w[i4 * 4 + 1], a2);
            a2 = fmaf(r.z, w[i4 * 4 + 2], a2); a2 = fmaf(r.w, w[i4 * 4 + 3], a2);
            a3 = fmaf(s.x, w[i4 * 4 + 0], a3); a3 = fmaf(s.y, w[i4 * 4 + 1], a3);
            a3 = fmaf(s.z, w[i4 * 4 + 2], a3); a3 = fmaf(s.w, w[i4 * 4 + 3], a3);
        }
        hp[(size_t)(n0 + 0) * HID_CH + lane] = a0;
        hp[(size_t)(n0 + 1) * HID_CH + lane] = a1;
        hp[(size_t)(n0 + 2) * HID_CH + lane] = a2;
        hp[(size_t)(n0 + 3) * HID_CH + lane] = a3;
    }
}

// ========== pre1: msg1[n][r][c] fp16; 2 groups (4+3 rels); VGPR budget 256 ==========
template<int RBASE, int NR>
__device__ __forceinline__ void pre1_work(const float* __restrict__ x,
                                          const float* __restrict__ W1,
                                          __half* __restrict__ msg1,
                                          int wid, int nw)
{
    const int lane = threadIdx.x & 63;
    const int b = lane >> 4;
    const int j = lane & 15;

    float w[NR][DI];  // 128 (or 96) weight VGPRs, static indices
#pragma unroll
    for (int rr = 0; rr < NR; ++rr) {
        const float* wp = W1 + ((size_t)((RBASE + rr) * NB + b) * DI) * DO + j;
#pragma unroll
        for (int i = 0; i < DI; ++i) w[rr][i] = wp[i * DO];
    }

    const int NPAIR = N_NODES / 2;
    for (int np = wid; np < NPAIR; np += nw) {
        const int n0 = np * 2;
        const float4* xr0 = (const float4*)(x + ((size_t)n0 << 7)) + (b << 3);
        const float4* xr1 = xr0 + 32;
        float4 xa[8], xb[8];
#pragma unroll
        for (int i4 = 0; i4 < 8; ++i4) { xa[i4] = xr0[i4]; xb[i4] = xr1[i4]; }
        __half* m0 = msg1 + (size_t)n0 * (N_REL * HID_CH) + (RBASE << 6) + lane;
        __half* m1 = m0 + N_REL * HID_CH;
#pragma unroll
        for (int rr = 0; rr < NR; ++rr) {
            float s0 = 0.f, s1 = 0.f;
#pragma unroll
            for (int i4 = 0; i4 < 8; ++i4) {
                s0 = fmaf(xa[i4].x, w[rr][i4 * 4 + 0], s0);
                s0 = fmaf(xa[i4].y, w[rr][i4 * 4 + 1], s0);
                s0 = fmaf(xa[i4].z, w[rr][i4 * 4 + 2], s0);
                s0 = fmaf(xa[i4].w, w[rr][i4 * 4 + 3], s0);
                s1 = fmaf(xb[i4].x, w[rr][i4 * 4 + 0], s1);
                s1 = fmaf(xb[i4].y, w[rr][i4 * 4 + 1], s1);
                s1 = fmaf(xb[i4].z, w[rr][i4 * 4 + 2], s1);
                s1 = fmaf(xb[i4].w, w[rr][i4 * 4 + 3], s1);
            }
            m0[rr << 6] = __float2half(s0);
            m1[rr << 6] = __float2half(s1);
        }
    }
}

__global__ __launch_bounds__(256, 2)
void pre1_kernel(const float* __restrict__ x, const float* __restrict__ W1,
                 __half* __restrict__ msg1)
{
    const int grp = blockIdx.x & 1;
    const int wid = (blockIdx.x >> 1) * 4 + (threadIdx.x >> 6);
    const int nw = (gridDim.x >> 1) * 4;
    if (grp == 0) pre1_work<0, 4>(x, W1, msg1, wid, nw);
    else          pre1_work<4, 3>(x, W1, msg1, wid, nw);
}

// ========== agg1: wave/node; ONE merged edge loop (rel-sorted) ==========
// running (prev_r, cur, add): add += cur at each rel change; control is wave-uniform.
__global__ __launch_bounds__(256)
void agg1_kernel(const __half* __restrict__ msg1, const float* __restrict__ hrootp,
                 const float* __restrict__ bias1, const int* __restrict__ off2,
                 const int* __restrict__ packed1, float* __restrict__ h)
{
    const int lane = threadIdx.x & 63;
    const int lane2 = lane * 2;
    const char* m1 = (const char*)msg1;
    const int wid = blockIdx.x * 4 + (threadIdx.x >> 6);
    const int nw = gridDim.x * 4;
    const float bias = bias1[lane];

    for (int n = wid; n < N_NODES; n += nw) {
        const int st = off2[n << 3];
        const int en = off2[(n << 3) + 7];
        float add = 0.f, cur = 0.f;
        int prev_r = -1;

#define MRG(kk, vv) { \
        int r_ = (int)((kk) >> 28); \
        bool same_ = (r_ == prev_r); \
        add += same_ ? 0.f : cur; \
        cur = same_ ? fmaxf(cur, (vv)) : (vv); \
        prev_r = r_; }

        int p = st;
        for (; p + 3 < en; p += 4) {  // 4 gathers in flight
            unsigned k0 = (unsigned)packed1[p];
            unsigned k1 = (unsigned)packed1[p + 1];
            unsigned k2 = (unsigned)packed1[p + 2];
            unsigned k3 = (unsigned)packed1[p + 3];
            float v0 = __half2float(*(const __half*)(m1 + (k0 & OFFM) + lane2));
            float v1 = __half2float(*(const __half*)(m1 + (k1 & OFFM) + lane2));
            float v2 = __half2float(*(const __half*)(m1 + (k2 & OFFM) + lane2));
            float v3 = __half2float(*(const __half*)(m1 + (k3 & OFFM) + lane2));
            MRG(k0, v0) MRG(k1, v1) MRG(k2, v2) MRG(k3, v3)
        }
        for (; p < en; ++p) {
            unsigned k0 = (unsigned)packed1[p];
            float v0 = __half2float(*(const __half*)(m1 + (k0 & OFFM) + lane2));
            MRG(k0, v0)
        }
#undef MRG
        add += cur;  // close last segment (0 if no edges)

        const size_t hi = ((size_t)n << 6) + lane;
        float v = hrootp[hi] + hrootp[(size_t)N_NODES * HID_CH + hi] + bias + add;
        h[hi] = fmaxf(v, 0.f);
    }
}

// ========== pre2: msg2[n][16] = [h@W2[0..6] (2 each), h@root2+bias2 (2)] ==========
__global__ __launch_bounds__(256)
void pre2_kernel(const float* __restrict__ h, const float* __restrict__ comp2,
                 const float* __restrict__ basis2, const float* __restrict__ root2,
                 const float* __restrict__ bias2, float* __restrict__ msg2)
{
    const int lane = threadIdx.x & 63;
    const int sub = lane >> 4;   // node within quad
    const int o = lane & 15;     // output column 0..15

    float w[64];
    if (o < 14) {
        const int r = o >> 1, oc = o & 1;
        float c0 = comp2[r * NB + 0], c1 = comp2[r * NB + 1];
        float c2 = comp2[r * NB + 2], c3 = comp2[r * NB + 3];
#pragma unroll
        for (int i = 0; i < 64; ++i) {
            w[i] = c0 * basis2[(0 * HID_CH + i) * OUT_CH + oc]
                 + c1 * basis2[(1 * HID_CH + i) * OUT_CH + oc]
                 + c2 * basis2[(2 * HID_CH + i) * OUT_CH + oc]
                 + c3 * basis2[(3 * HID_CH + i) * OUT_CH + oc];
        }
    } else {
        const int oc = o - 14;
#pragma unroll
        for (int i = 0; i < 64; ++i) w[i] = root2[i * OUT_CH + oc];
    }
    const float badd = (o == 14) ? bias2[0] : ((o == 15) ? bias2[1] : 0.f);

    const int wid = blockIdx.x * 4 + (threadIdx.x >> 6);
    const int nw = gridDim.x * 4;
    const int NQUAD = N_NODES / 4;

    for (int nq = wid; nq < NQUAD; nq += nw) {
        const int n = nq * 4 + sub;
        const float4* hr = (const float4*)(h + ((size_t)n << 6));
        float acc = badd;
#pragma unroll
        for (int i4 = 0; i4 < 16; ++i4) {
            float4 hv = hr[i4];
            acc = fmaf(hv.x, w[i4 * 4 + 0], acc);
            acc = fmaf(hv.y, w[i4 * 4 + 1], acc);
            acc = fmaf(hv.z, w[i4 * 4 + 2], acc);
            acc = fmaf(hv.w, w[i4 * 4 + 3], acc);
        }
        msg2[(size_t)nq * 64 + lane] = acc;  // == msg2[n*16 + o]
    }
}

// ========== agg2: thread/node; ONE merged edge loop over float2 msgs ==========
__global__ __launch_bounds__(256)
void agg2_kernel(const float* __restrict__ msg2, const int* __restrict__ off2,
                 const int* __restrict__ packed2, float* __restrict__ out)
{
    const int n = blockIdx.x * blockDim.x + threadIdx.x;
    if (n >= N_NODES) return;
    const char* m2 = (const char*)msg2;
    const int st = off2[n << 3];
    const int en = off2[(n << 3) + 7];
    float addx = 0.f, addy = 0.f, curx = 0.f, cury = 0.f;
    int prev_r = -1;

#define MRG2(kk, ff) { \
    int r_ = ((kk) >> 3) & 7; \
    bool same_ = (r_ == prev_r); \
    addx += same_ ? 0.f : curx; \
    addy += same_ ? 0.f : cury; \
    curx = same_ ? fmaxf(curx, (ff).x) : (ff).x; \
    cury = same_ ? fmaxf(cury, (ff).y) : (ff).y; \
    prev_r = r_; }

    int p = st;
    for (; p + 1 < en; p += 2) {
        int k0 = packed2[p], k1 = packed2[p + 1];
        float2 f0 = *(const float2*)(m2 + k0);
        float2 f1 = *(const float2*)(m2 + k1);
        MRG2(k0, f0) MRG2(k1, f1)
    }
    if (p < en) {
        int k0 = packed2[p];
        float2 f0 = *(const float2*)(m2 + k0);
        MRG2(k0, f0)
    }
#undef MRG2

    out[(size_t)n * OUT_CH + 0] = msg2[(size_t)n * 16 + 14] + addx + curx;
    out[(size_t)n * OUT_CH + 1] = msg2[(size_t)n * 16 + 15] + addy + cury;
}

extern "C" void kernel_launch(void* const* d_in, const int* in_sizes, int n_in,
                              void* d_out, int out_size, void* d_ws, size_t ws_size,
                              hipStream_t stream)
{
    const float* x      = (const float*)d_in[0];
    const int*   ei     = (const int*)d_in[1];
    const int*   et     = (const int*)d_in[2];
    const float* W1     = (const float*)d_in[3];
    const float* root1  = (const float*)d_in[4];
    const float* bias1  = (const float*)d_in[5];
    const float* comp2  = (const float*)d_in[6];
    const float* basis2 = (const float*)d_in[7];
    const float* root2  = (const float*)d_in[8];
    const float* bias2  = (const float*)d_in[9];
    float* out = (float*)d_out;

    // workspace carve-up (~191 MB)
    char* ws = (char*)d_ws;
    size_t o = 0;
    auto carve = [&](size_t bytes) { char* p = ws + o; o += (bytes + 255) & ~(size_t)255; return p; };
    int*    deg2    = (int*)carve(sizeof(int) * NBINS);
    int*    off2    = (int*)carve(sizeof(int) * (NBINS + 1));
    int*    cursor2 = (int*)carve(sizeof(int) * (NBINS + 1));
    int*    sums    = (int*)carve(sizeof(int) * 1024);
    int*    packed1 = (int*)carve(sizeof(int) * N_EDGESV);
    int*    packed2 = (int*)carve(sizeof(int) * N_EDGESV);
    __half* msg1    = (__half*)carve(sizeof(__half) * (size_t)N_NODES * N_REL * HID_CH);  // 89.6 MB
    float*  hrootp  = (float*)carve(sizeof(float) * 2 * (size_t)N_NODES * HID_CH);        // 51.2 MB
    float*  h       = (float*)carve(sizeof(float) * (size_t)N_NODES * HID_CH);            // 25.6 MB
    float*  msg2    = (float*)carve(sizeof(float) * (size_t)N_NODES * 16);                //  6.4 MB

    // ---- CSR build over (dst, rel) ----
    hipMemsetAsync(deg2, 0, sizeof(int) * NBINS, stream);
    hist_kernel<<<(N_EDGESV + 255) / 256, 256, 0, stream>>>(ei, et, deg2);
    scan1_kernel<<<NCHUNK2, 256, 0, stream>>>(deg2, off2, sums);
    scan2_kernel<<<1, 1024, 0, stream>>>(sums);
    scan3_kernel<<<(NBINS + 255) / 256, 256, 0, stream>>>(off2, sums, cursor2);
    scatter_kernel<<<(N_EDGESV + 255) / 256, 256, 0, stream>>>(ei, et, cursor2, packed1, packed2);

    // ---- dense precomputes ----
    rootmm_kernel<0><<<512, 256, 0, stream>>>(x, root1, hrootp);
    rootmm_kernel<1><<<512, 256, 0, stream>>>(x, root1, hrootp);
    pre1_kernel<<<2048, 256, 0, stream>>>(x, W1, msg1);

    // ---- layer 1 aggregation ----
    agg1_kernel<<<2048, 256, 0, stream>>>(msg1, hrootp, bias1, off2, packed1, h);

    // ---- layer 2 dense messages + aggregation ----
    pre2_kernel<<<1024, 256, 0, stream>>>(h, comp2, basis2, root2, bias2, msg2);
    agg2_kernel<<<(N_NODES + 255) / 256, 256, 0, stream>>>(msg2, off2, packed2, out);
}

// Round 10
// 410.963 us; speedup vs baseline: 1.5256x; 1.3061x over previous
//
#include <hip/hip_runtime.h>

#define N_NODES 100000
#define N_EDGESV 1000000
#define N_REL 7
#define IN_CH 128
#define HID_CH 64
#define NBINS 800000          // (dst, rel) bins: key = d*8 + r
#define SCAN_CHUNK 1024
#define NCHUNK2 ((NBINS + SCAN_CHUNK - 1) / SCAN_CHUNK)  // 782
#define OFFM 0x0FFFFFFFu
#define NTILES 6250           // N_NODES / 16

typedef _Float16 f16;
typedef __attribute__((ext_vector_type(8))) _Float16 f16x8;
typedef __attribute__((ext_vector_type(4))) _Float16 f16x4;
typedef __attribute__((ext_vector_type(4))) float f32x4;

// ================= CSR build over (dst, rel) keys =================
__global__ void hist_kernel(const int* __restrict__ ei, const int* __restrict__ et,
                            int* __restrict__ deg2) {
    int e = blockIdx.x * blockDim.x + threadIdx.x;
    if (e < N_EDGESV) atomicAdd(&deg2[(ei[N_EDGESV + e] << 3) + et[e]], 1);
}

__global__ void scan1_kernel(const int* __restrict__ deg2, int* __restrict__ off2,
                             int* __restrict__ sums) {
    __shared__ int lds[256];
    const int tid = threadIdx.x;
    const int base = blockIdx.x * SCAN_CHUNK + tid * 4;
    int v0 = (base + 0 < NBINS) ? deg2[base + 0] : 0;
    int v1 = (base + 1 < NBINS) ? deg2[base + 1] : 0;
    int v2 = (base + 2 < NBINS) ? deg2[base + 2] : 0;
    int v3 = (base + 3 < NBINS) ? deg2[base + 3] : 0;
    int t0 = v0, t1 = v0 + v1, t2 = t1 + v2, t3 = t2 + v3;
    lds[tid] = t3;
    __syncthreads();
    for (int d = 1; d < 256; d <<= 1) {
        int t = (tid >= d) ? lds[tid - d] : 0;
        __syncthreads();
        if (tid >= d) lds[tid] += t;
        __syncthreads();
    }
    int excl = lds[tid] - t3;
    if (base + 0 < NBINS) off2[base + 1] = excl + t0;
    if (base + 1 < NBINS) off2[base + 2] = excl + t1;
    if (base + 2 < NBINS) off2[base + 3] = excl + t2;
    if (base + 3 < NBINS) off2[base + 4] = excl + t3;
    if (tid == 255) sums[blockIdx.x] = lds[255];
}

__global__ void scan2_kernel(int* __restrict__ sums) {
    __shared__ int lds[1024];
    int t = threadIdx.x;
    lds[t] = (t < NCHUNK2) ? sums[t] : 0;
    __syncthreads();
    for (int d = 1; d < 1024; d <<= 1) {
        int v = (t >= d) ? lds[t - d] : 0;
        __syncthreads();
        if (t >= d) lds[t] += v;
        __syncthreads();
    }
    if (t < NCHUNK2) sums[t] = lds[t];
}

__global__ void scan3_kernel(int* __restrict__ off2, const int* __restrict__ sums,
                             int* __restrict__ cursor2) {
    int i = blockIdx.x * blockDim.x + threadIdx.x;
    if (i == 0) { off2[0] = 0; cursor2[0] = 0; }
    if (i < NBINS) {
        int chunk = i / SCAN_CHUNK;
        int v = off2[i + 1] + ((chunk > 0) ? sums[chunk - 1] : 0);
        off2[i + 1] = v;
        cursor2[i + 1] = v;
    }
}

// packed1: (byte off into msg1 = s*896 + r*128) | r<<28 ; packed2: s*64 + r*8
__global__ void scatter_kernel(const int* __restrict__ ei, const int* __restrict__ et,
                               int* __restrict__ cursor2, int* __restrict__ packed1,
                               int* __restrict__ packed2) {
    int e = blockIdx.x * blockDim.x + threadIdx.x;
    if (e < N_EDGESV) {
        int d = ei[N_EDGESV + e];
        int s = ei[e];
        int r = et[e];
        int pos = atomicAdd(&cursor2[(d << 3) + r], 1);
        packed1[pos] = (s * 896 + r * 128) | (r << 28);
        packed2[pos] = s * 64 + r * 8;
    }
}

// ========== xh: x fp32 -> fp16 ==========
__global__ __launch_bounds__(256)
void xh_kernel(const float* __restrict__ x, f16* __restrict__ xh) {
    int i = blockIdx.x * blockDim.x + threadIdx.x;  // one float4 per thread
    if (i < N_NODES * IN_CH / 4) {
        float4 v = ((const float4*)x)[i];
        f16x4 o = {(f16)v.x, (f16)v.y, (f16)v.z, (f16)v.w};
        *(f16x4*)(xh + (size_t)i * 4) = o;
    }
}

// ========== wbuild: Wb_t[512][128] fp16 (col-major GEMM B) + W2_t[16][64] ==========
// Wb_t col c: c<64 -> root1[:,c]; c=64+r*64+b*16+j -> block-diag W1[r][b][:,j]
__global__ void wbuild_kernel(const float* __restrict__ root1, const float* __restrict__ W1,
                              const float* __restrict__ comp2, const float* __restrict__ basis2,
                              const float* __restrict__ root2, f16* __restrict__ wbt,
                              f16* __restrict__ w2t) {
    for (int idx = blockIdx.x * blockDim.x + threadIdx.x; idx < 512 * 128;
         idx += gridDim.x * blockDim.x) {
        int col = idx >> 7, k = idx & 127;
        float v;
        if (col < 64) {
            v = root1[k * HID_CH + col];
        } else {
            int cc = col - 64, r = cc >> 6, inner = cc & 63, b = inner >> 4, j = inner & 15;
            int kb = k - b * 32;
            v = (kb >= 0 && kb < 32) ? W1[(((r * 4 + b) * 32) + kb) * 16 + j] : 0.f;
        }
        wbt[idx] = (f16)v;
    }
    for (int idx = blockIdx.x * blockDim.x + threadIdx.x; idx < 16 * 64;
         idx += gridDim.x * blockDim.x) {
        int col = idx >> 6, k = idx & 63;
        float v;
        if (col < 14) {
            int r = col >> 1, oc = col & 1;
            v = 0.f;
            for (int b = 0; b < 4; ++b) v += comp2[r * 4 + b] * basis2[(b * 64 + k) * 2 + oc];
        } else {
            v = root2[k * 2 + (col - 14)];
        }
        w2t[idx] = (f16)v;
    }
}

// ========== gemm1 (MFMA): [16-node tile] x [512 cols], K=128 ==========
// out cols 0..63 -> hroot fp32 ; cols 64..511 -> msg1 fp16 [n][448]
// A[m=lane&15][k=quad*8+j] ; B[k=quad*8+j][n=lane&15] ; D[row=quad*4+i][col=lane&15]
__global__ __launch_bounds__(256)
void gemm1_kernel(const f16* __restrict__ xh, const f16* __restrict__ wbt,
                  float* __restrict__ hroot, f16* __restrict__ msg1) {
    const int lane = threadIdx.x & 63;
    const int wv = threadIdx.x >> 6;
    const int n0 = blockIdx.x * 16;
    const int m = lane & 15;
    const int quad = lane >> 4;

    f16x8 a[4];
    const f16* xrow = xh + (size_t)(n0 + m) * 128 + quad * 8;
#pragma unroll
    for (int kk = 0; kk < 4; ++kk) a[kk] = *(const f16x8*)(xrow + kk * 32);

#pragma unroll
    for (int t = 0; t < 8; ++t) {
        const int c0 = (wv * 8 + t) * 16;
        const f16* wcol = wbt + (size_t)(c0 + m) * 128 + quad * 8;
        f32x4 acc = {0.f, 0.f, 0.f, 0.f};
#pragma unroll
        for (int kk = 0; kk < 4; ++kk) {
            f16x8 b = *(const f16x8*)(wcol + kk * 32);
            acc = __builtin_amdgcn_mfma_f32_16x16x32_f16(a[kk], b, acc, 0, 0, 0);
        }
        if (c0 < 64) {
            const int col = c0 + m;
#pragma unroll
            for (int i = 0; i < 4; ++i)
                hroot[(size_t)(n0 + quad * 4 + i) * 64 + col] = acc[i];
        } else {
            const int cc = c0 - 64 + m;
#pragma unroll
            for (int i = 0; i < 4; ++i)
                msg1[(size_t)(n0 + quad * 4 + i) * 448 + cc] = (f16)acc[i];
        }
    }
}

// ========== agg1: wave/node; merged rel-sorted edge loop; writes h fp16 ==========
__global__ __launch_bounds__(256)
void agg1_kernel(const f16* __restrict__ msg1, const float* __restrict__ hroot,
                 const float* __restrict__ bias1, const int* __restrict__ off2,
                 const int* __restrict__ packed1, f16* __restrict__ h16)
{
    const int lane = threadIdx.x & 63;
    const int lane2 = lane * 2;
    const char* m1 = (const char*)msg1;
    const int wid = blockIdx.x * 4 + (threadIdx.x >> 6);
    const int nw = gridDim.x * 4;
    const float bias = bias1[lane];

    for (int n = wid; n < N_NODES; n += nw) {
        const int st = off2[n << 3];
        const int en = off2[(n << 3) + 7];
        float add = 0.f, cur = 0.f;
        int prev_r = -1;

#define MRG(kk, vv) { \
        int r_ = (int)((kk) >> 28); \
        bool same_ = (r_ == prev_r); \
        add += same_ ? 0.f : cur; \
        cur = same_ ? fmaxf(cur, (vv)) : (vv); \
        prev_r = r_; }

        int p = st;
        for (; p + 3 < en; p += 4) {
            unsigned k0 = (unsigned)packed1[p];
            unsigned k1 = (unsigned)packed1[p + 1];
            unsigned k2 = (unsigned)packed1[p + 2];
            unsigned k3 = (unsigned)packed1[p + 3];
            float v0 = (float)*(const f16*)(m1 + (k0 & OFFM) + lane2);
            float v1 = (float)*(const f16*)(m1 + (k1 & OFFM) + lane2);
            float v2 = (float)*(const f16*)(m1 + (k2 & OFFM) + lane2);
            float v3 = (float)*(const f16*)(m1 + (k3 & OFFM) + lane2);
            MRG(k0, v0) MRG(k1, v1) MRG(k2, v2) MRG(k3, v3)
        }
        for (; p < en; ++p) {
            unsigned k0 = (unsigned)packed1[p];
            float v0 = (float)*(const f16*)(m1 + (k0 & OFFM) + lane2);
            MRG(k0, v0)
        }
#undef MRG
        add += cur;

        const size_t hi = ((size_t)n << 6) + lane;
        h16[hi] = (f16)fmaxf(hroot[hi] + bias + add, 0.f);
    }
}

// ========== pre2 (MFMA): msg2[n][16] = h[16-tile] @ W2_t^T (+bias on cols 14/15) ==========
__global__ __launch_bounds__(256)
void pre2_kernel(const f16* __restrict__ h16, const f16* __restrict__ w2t,
                 const float* __restrict__ bias2, float* __restrict__ msg2) {
    const int lane = threadIdx.x & 63;
    const int wv = threadIdx.x >> 6;
    const int nt = blockIdx.x * 4 + wv;
    if (nt >= NTILES) return;
    const int n0 = nt * 16;
    const int m = lane & 15;
    const int quad = lane >> 4;

    const f16* hrow = h16 + (size_t)(n0 + m) * 64 + quad * 8;
    const f16* wcol = w2t + (size_t)m * 64 + quad * 8;
    f32x4 acc = {0.f, 0.f, 0.f, 0.f};
    f16x8 a0 = *(const f16x8*)(hrow);
    f16x8 b0 = *(const f16x8*)(wcol);
    acc = __builtin_amdgcn_mfma_f32_16x16x32_f16(a0, b0, acc, 0, 0, 0);
    f16x8 a1 = *(const f16x8*)(hrow + 32);
    f16x8 b1 = *(const f16x8*)(wcol + 32);
    acc = __builtin_amdgcn_mfma_f32_16x16x32_f16(a1, b1, acc, 0, 0, 0);

    const float badd = (m == 14) ? bias2[0] : ((m == 15) ? bias2[1] : 0.f);
#pragma unroll
    for (int i = 0; i < 4; ++i)
        msg2[(size_t)(n0 + quad * 4 + i) * 16 + m] = acc[i] + badd;
}

// ========== agg2: thread/node; merged edge loop over float2 msgs ==========
__global__ __launch_bounds__(256)
void agg2_kernel(const float* __restrict__ msg2, const int* __restrict__ off2,
                 const int* __restrict__ packed2, float* __restrict__ out)
{
    const int n = blockIdx.x * blockDim.x + threadIdx.x;
    if (n >= N_NODES) return;
    const char* m2 = (const char*)msg2;
    const int st = off2[n << 3];
    const int en = off2[(n << 3) + 7];
    float addx = 0.f, addy = 0.f, curx = 0.f, cury = 0.f;
    int prev_r = -1;

#define MRG2(kk, ff) { \
    int r_ = ((kk) >> 3) & 7; \
    bool same_ = (r_ == prev_r); \
    addx += same_ ? 0.f : curx; \
    addy += same_ ? 0.f : cury; \
    curx = same_ ? fmaxf(curx, (ff).x) : (ff).x; \
    cury = same_ ? fmaxf(cury, (ff).y) : (ff).y; \
    prev_r = r_; }

    int p = st;
    for (; p + 1 < en; p += 2) {
        int k0 = packed2[p], k1 = packed2[p + 1];
        float2 f0 = *(const float2*)(m2 + k0);
        float2 f1 = *(const float2*)(m2 + k1);
        MRG2(k0, f0) MRG2(k1, f1)
    }
    if (p < en) {
        int k0 = packed2[p];
        float2 f0 = *(const float2*)(m2 + k0);
        MRG2(k0, f0)
    }
#undef MRG2

    out[(size_t)n * 2 + 0] = msg2[(size_t)n * 16 + 14] + addx + curx;
    out[(size_t)n * 2 + 1] = msg2[(size_t)n * 16 + 15] + addy + cury;
}

extern "C" void kernel_launch(void* const* d_in, const int* in_sizes, int n_in,
                              void* d_out, int out_size, void* d_ws, size_t ws_size,
                              hipStream_t stream)
{
    const float* x      = (const float*)d_in[0];
    const int*   ei     = (const int*)d_in[1];
    const int*   et     = (const int*)d_in[2];
    const float* W1     = (const float*)d_in[3];
    const float* root1  = (const float*)d_in[4];
    const float* bias1  = (const float*)d_in[5];
    const float* comp2  = (const float*)d_in[6];
    const float* basis2 = (const float*)d_in[7];
    const float* root2  = (const float*)d_in[8];
    const float* bias2  = (const float*)d_in[9];
    float* out = (float*)d_out;

    // workspace carve-up (~180 MB)
    char* ws = (char*)d_ws;
    size_t o = 0;
    auto carve = [&](size_t bytes) { char* p = ws + o; o += (bytes + 255) & ~(size_t)255; return p; };
    int*   deg2    = (int*)carve(sizeof(int) * NBINS);
    int*   off2    = (int*)carve(sizeof(int) * (NBINS + 1));
    int*   cursor2 = (int*)carve(sizeof(int) * (NBINS + 1));
    int*   sums    = (int*)carve(sizeof(int) * 1024);
    int*   packed1 = (int*)carve(sizeof(int) * N_EDGESV);
    int*   packed2 = (int*)carve(sizeof(int) * N_EDGESV);
    f16*   xh      = (f16*)carve(sizeof(f16) * (size_t)N_NODES * IN_CH);            // 25.6 MB
    f16*   wbt     = (f16*)carve(sizeof(f16) * 512 * 128);                          // 128 KB
    f16*   w2t     = (f16*)carve(sizeof(f16) * 16 * 64);                            //   2 KB
    f16*   msg1    = (f16*)carve(sizeof(f16) * (size_t)N_NODES * N_REL * HID_CH);   // 89.6 MB
    float* hroot   = (float*)carve(sizeof(float) * (size_t)N_NODES * HID_CH);       // 25.6 MB
    f16*   h16     = (f16*)carve(sizeof(f16) * (size_t)N_NODES * HID_CH);           // 12.8 MB
    float* msg2    = (float*)carve(sizeof(float) * (size_t)N_NODES * 16);           //  6.4 MB

    // ---- CSR build over (dst, rel) ----
    hipMemsetAsync(deg2, 0, sizeof(int) * NBINS, stream);
    hist_kernel<<<(N_EDGESV + 255) / 256, 256, 0, stream>>>(ei, et, deg2);
    scan1_kernel<<<NCHUNK2, 256, 0, stream>>>(deg2, off2, sums);
    scan2_kernel<<<1, 1024, 0, stream>>>(sums);
    scan3_kernel<<<(NBINS + 255) / 256, 256, 0, stream>>>(off2, sums, cursor2);
    scatter_kernel<<<(N_EDGESV + 255) / 256, 256, 0, stream>>>(ei, et, cursor2, packed1, packed2);

    // ---- fp16 staging + MFMA dense precompute ----
    xh_kernel<<<(N_NODES * IN_CH / 4 + 255) / 256, 256, 0, stream>>>(x, xh);
    wbuild_kernel<<<64, 256, 0, stream>>>(root1, W1, comp2, basis2, root2, wbt, w2t);
    gemm1_kernel<<<NTILES, 256, 0, stream>>>(xh, wbt, hroot, msg1);

    // ---- layer 1 aggregation ----
    agg1_kernel<<<2048, 256, 0, stream>>>(msg1, hroot, bias1, off2, packed1, h16);

    // ---- layer 2: MFMA messages + aggregation ----
    pre2_kernel<<<(NTILES + 3) / 4, 256, 0, stream>>>(h16, w2t, bias2, msg2);
    agg2_kernel<<<(N_NODES + 255) / 256, 256, 0, stream>>>(msg2, off2, packed2, out);
}

// Round 11
// 344.064 us; speedup vs baseline: 1.8222x; 1.1944x over previous
//
#include <hip/hip_runtime.h>

#define N_NODES 100000
#define N_EDGESV 1000000
#define N_REL 7
#define IN_CH 128
#define HID_CH 64
#define NBINS 800000          // (dst, rel) bins: key = d*8 + r
#define SCAN_CHUNK 1024
#define NCHUNK2 ((NBINS + SCAN_CHUNK - 1) / SCAN_CHUNK)  // 782
#define OFFM 0x0FFFFFFFu
#define NTILES 6250           // N_NODES / 16
#define GSTRIDE 520           // LDS row stride (f16): +8 pad -> rows shift 4 banks

typedef _Float16 f16;
typedef __attribute__((ext_vector_type(8))) _Float16 f16x8;
typedef __attribute__((ext_vector_type(4))) _Float16 f16x4;
typedef __attribute__((ext_vector_type(4))) float f32x4;

// ================= CSR build over (dst, rel) keys =================
__global__ void hist_kernel(const int* __restrict__ ei, const int* __restrict__ et,
                            int* __restrict__ deg2) {
    int e = blockIdx.x * blockDim.x + threadIdx.x;
    if (e < N_EDGESV) atomicAdd(&deg2[(ei[N_EDGESV + e] << 3) + et[e]], 1);
}

__global__ void scan1_kernel(const int* __restrict__ deg2, int* __restrict__ off2,
                             int* __restrict__ sums) {
    __shared__ int lds[256];
    const int tid = threadIdx.x;
    const int base = blockIdx.x * SCAN_CHUNK + tid * 4;
    int v0 = (base + 0 < NBINS) ? deg2[base + 0] : 0;
    int v1 = (base + 1 < NBINS) ? deg2[base + 1] : 0;
    int v2 = (base + 2 < NBINS) ? deg2[base + 2] : 0;
    int v3 = (base + 3 < NBINS) ? deg2[base + 3] : 0;
    int t0 = v0, t1 = v0 + v1, t2 = t1 + v2, t3 = t2 + v3;
    lds[tid] = t3;
    __syncthreads();
    for (int d = 1; d < 256; d <<= 1) {
        int t = (tid >= d) ? lds[tid - d] : 0;
        __syncthreads();
        if (tid >= d) lds[tid] += t;
        __syncthreads();
    }
    int excl = lds[tid] - t3;
    if (base + 0 < NBINS) off2[base + 1] = excl + t0;
    if (base + 1 < NBINS) off2[base + 2] = excl + t1;
    if (base + 2 < NBINS) off2[base + 3] = excl + t2;
    if (base + 3 < NBINS) off2[base + 4] = excl + t3;
    if (tid == 255) sums[blockIdx.x] = lds[255];
}

__global__ void scan2_kernel(int* __restrict__ sums) {
    __shared__ int lds[1024];
    int t = threadIdx.x;
    lds[t] = (t < NCHUNK2) ? sums[t] : 0;
    __syncthreads();
    for (int d = 1; d < 1024; d <<= 1) {
        int v = (t >= d) ? lds[t - d] : 0;
        __syncthreads();
        if (t >= d) lds[t] += v;
        __syncthreads();
    }
    if (t < NCHUNK2) sums[t] = lds[t];
}

__global__ void scan3_kernel(int* __restrict__ off2, const int* __restrict__ sums,
                             int* __restrict__ cursor2) {
    int i = blockIdx.x * blockDim.x + threadIdx.x;
    if (i == 0) { off2[0] = 0; cursor2[0] = 0; }
    if (i < NBINS) {
        int chunk = i / SCAN_CHUNK;
        int v = off2[i + 1] + ((chunk > 0) ? sums[chunk - 1] : 0);
        off2[i + 1] = v;
        cursor2[i + 1] = v;
    }
}

// packed1: (byte off into dense1 = s*1024 + 128 + r*128) | r<<28 ; packed2: s*64 + r*8
__global__ void scatter_kernel(const int* __restrict__ ei, const int* __restrict__ et,
                               int* __restrict__ cursor2, int* __restrict__ packed1,
                               int* __restrict__ packed2) {
    int e = blockIdx.x * blockDim.x + threadIdx.x;
    if (e < N_EDGESV) {
        int d = ei[N_EDGESV + e];
        int s = ei[e];
        int r = et[e];
        int pos = atomicAdd(&cursor2[(d << 3) + r], 1);
        packed1[pos] = (s * 1024 + 128 + r * 128) | (r << 28);
        packed2[pos] = s * 64 + r * 8;
    }
}

// ========== xh: x fp32 -> fp16 ==========
__global__ __launch_bounds__(256)
void xh_kernel(const float* __restrict__ x, f16* __restrict__ xh) {
    int i = blockIdx.x * blockDim.x + threadIdx.x;  // one float4 per thread
    if (i < N_NODES * IN_CH / 4) {
        float4 v = ((const float4*)x)[i];
        f16x4 o = {(f16)v.x, (f16)v.y, (f16)v.z, (f16)v.w};
        *(f16x4*)(xh + (size_t)i * 4) = o;
    }
}

// ========== wbuild: Wb_t[512][128] fp16 (col-major GEMM B) + W2_t[16][64] ==========
// Wb_t col c: c<64 -> root1[:,c]; c=64+r*64+b*16+j -> block-diag W1[r][b][:,j]
__global__ void wbuild_kernel(const float* __restrict__ root1, const float* __restrict__ W1,
                              const float* __restrict__ comp2, const float* __restrict__ basis2,
                              const float* __restrict__ root2, f16* __restrict__ wbt,
                              f16* __restrict__ w2t) {
    for (int idx = blockIdx.x * blockDim.x + threadIdx.x; idx < 512 * 128;
         idx += gridDim.x * blockDim.x) {
        int col = idx >> 7, k = idx & 127;
        float v;
        if (col < 64) {
            v = root1[k * HID_CH + col];
        } else {
            int cc = col - 64, r = cc >> 6, inner = cc & 63, b = inner >> 4, j = inner & 15;
            int kb = k - b * 32;
            v = (kb >= 0 && kb < 32) ? W1[(((r * 4 + b) * 32) + kb) * 16 + j] : 0.f;
        }
        wbt[idx] = (f16)v;
    }
    for (int idx = blockIdx.x * blockDim.x + threadIdx.x; idx < 16 * 64;
         idx += gridDim.x * blockDim.x) {
        int col = idx >> 6, k = idx & 63;
        float v;
        if (col < 14) {
            int r = col >> 1, oc = col & 1;
            v = 0.f;
            for (int b = 0; b < 4; ++b) v += comp2[r * 4 + b] * basis2[(b * 64 + k) * 2 + oc];
        } else {
            v = root2[k * 2 + (col - 14)];
        }
        w2t[idx] = (f16)v;
    }
}

// ========== gemm1 (MFMA): dense1[n][512] f16 = xh @ Wb_t^T ==========
// 8 waves/block; wave w owns cols [64w,64w+64): B frags live in VGPRs across all
// M-tiles (grid-stride). C staged via LDS -> 1KB-contiguous row stores.
__global__ __launch_bounds__(512, 2)
void gemm1_kernel(const f16* __restrict__ xh, const f16* __restrict__ wbt,
                  f16* __restrict__ dense1) {
    __shared__ f16 cbuf[16 * GSTRIDE];  // 16640 B
    const int lane = threadIdx.x & 63;
    const int wv = threadIdx.x >> 6;    // 0..7
    const int m = lane & 15;
    const int quad = lane >> 4;

    // preload this wave's 16 B fragments (4 col-tiles x 4 K-frags), static indices
    f16x8 bf[4][4];
#pragma unroll
    for (int t = 0; t < 4; ++t) {
        const f16* wc = wbt + (size_t)(wv * 64 + t * 16 + m) * 128 + quad * 8;
#pragma unroll
        for (int kk = 0; kk < 4; ++kk)
            bf[t][kk] = *(const f16x8*)(wc + kk * 32);
    }

    for (int tile = blockIdx.x; tile < NTILES; tile += gridDim.x) {
        const int n0 = tile * 16;
        const f16* xrow = xh + (size_t)(n0 + m) * 128 + quad * 8;
        f16x8 a[4];
#pragma unroll
        for (int kk = 0; kk < 4; ++kk) a[kk] = *(const f16x8*)(xrow + kk * 32);

#pragma unroll
        for (int t = 0; t < 4; ++t) {
            f32x4 acc = {0.f, 0.f, 0.f, 0.f};
#pragma unroll
            for (int kk = 0; kk < 4; ++kk)
                acc = __builtin_amdgcn_mfma_f32_16x16x32_f16(a[kk], bf[t][kk], acc, 0, 0, 0);
            const int col = wv * 64 + t * 16 + m;
#pragma unroll
            for (int i = 0; i < 4; ++i)
                cbuf[(quad * 4 + i) * GSTRIDE + col] = (f16)acc[i];
        }
        __syncthreads();
        // coalesced write-out: each wave writes 2 rows of 512 f16 (1 KB contiguous)
#pragma unroll
        for (int rr = 0; rr < 2; ++rr) {
            const int row = wv * 2 + rr;
            f16x8 v = *(const f16x8*)(cbuf + row * GSTRIDE + lane * 8);
            *(f16x8*)(dense1 + (size_t)(n0 + row) * 512 + lane * 8) = v;
        }
        __syncthreads();
    }
}

// ========== agg1: wave/node; merged rel-sorted edge loop; writes h fp16 ==========
__global__ __launch_bounds__(256)
void agg1_kernel(const f16* __restrict__ dense1, const float* __restrict__ bias1,
                 const int* __restrict__ off2, const int* __restrict__ packed1,
                 f16* __restrict__ h16)
{
    const int lane = threadIdx.x & 63;
    const int lane2 = lane * 2;
    const char* m1 = (const char*)dense1;
    const int wid = blockIdx.x * 4 + (threadIdx.x >> 6);
    const int nw = gridDim.x * 4;
    const float bias = bias1[lane];

    for (int n = wid; n < N_NODES; n += nw) {
        const int st = off2[n << 3];
        const int en = off2[(n << 3) + 7];
        float add = 0.f, cur = 0.f;
        int prev_r = -1;

#define MRG(kk, vv) { \
        int r_ = (int)((kk) >> 28); \
        bool same_ = (r_ == prev_r); \
        add += same_ ? 0.f : cur; \
        cur = same_ ? fmaxf(cur, (vv)) : (vv); \
        prev_r = r_; }

        int p = st;
        for (; p + 3 < en; p += 4) {
            unsigned k0 = (unsigned)packed1[p];
            unsigned k1 = (unsigned)packed1[p + 1];
            unsigned k2 = (unsigned)packed1[p + 2];
            unsigned k3 = (unsigned)packed1[p + 3];
            float v0 = (float)*(const f16*)(m1 + (k0 & OFFM) + lane2);
            float v1 = (float)*(const f16*)(m1 + (k1 & OFFM) + lane2);
            float v2 = (float)*(const f16*)(m1 + (k2 & OFFM) + lane2);
            float v3 = (float)*(const f16*)(m1 + (k3 & OFFM) + lane2);
            MRG(k0, v0) MRG(k1, v1) MRG(k2, v2) MRG(k3, v3)
        }
        for (; p < en; ++p) {
            unsigned k0 = (unsigned)packed1[p];
            float v0 = (float)*(const f16*)(m1 + (k0 & OFFM) + lane2);
            MRG(k0, v0)
        }
#undef MRG
        add += cur;

        // hroot lives in dense1 cols 0..63 (fp16)
        const float hroot = (float)dense1[(size_t)n * 512 + lane];
        h16[((size_t)n << 6) + lane] = (f16)fmaxf(hroot + bias + add, 0.f);
    }
}

// ========== pre2 (MFMA): msg2[n][16] = h[16-tile] @ W2_t^T (+bias on cols 14/15) ==========
__global__ __launch_bounds__(256)
void pre2_kernel(const f16* __restrict__ h16, const f16* __restrict__ w2t,
                 const float* __restrict__ bias2, float* __restrict__ msg2) {
    const int lane = threadIdx.x & 63;
    const int wv = threadIdx.x >> 6;
    const int nt = blockIdx.x * 4 + wv;
    if (nt >= NTILES) return;
    const int n0 = nt * 16;
    const int m = lane & 15;
    const int quad = lane >> 4;

    const f16* hrow = h16 + (size_t)(n0 + m) * 64 + quad * 8;
    const f16* wcol = w2t + (size_t)m * 64 + quad * 8;
    f32x4 acc = {0.f, 0.f, 0.f, 0.f};
    f16x8 a0 = *(const f16x8*)(hrow);
    f16x8 b0 = *(const f16x8*)(wcol);
    acc = __builtin_amdgcn_mfma_f32_16x16x32_f16(a0, b0, acc, 0, 0, 0);
    f16x8 a1 = *(const f16x8*)(hrow + 32);
    f16x8 b1 = *(const f16x8*)(wcol + 32);
    acc = __builtin_amdgcn_mfma_f32_16x16x32_f16(a1, b1, acc, 0, 0, 0);

    const float badd = (m == 14) ? bias2[0] : ((m == 15) ? bias2[1] : 0.f);
#pragma unroll
    for (int i = 0; i < 4; ++i)
        msg2[(size_t)(n0 + quad * 4 + i) * 16 + m] = acc[i] + badd;
}

// ========== agg2: thread/node; merged edge loop over float2 msgs ==========
__global__ __launch_bounds__(256)
void agg2_kernel(const float* __restrict__ msg2, const int* __restrict__ off2,
                 const int* __restrict__ packed2, float* __restrict__ out)
{
    const int n = blockIdx.x * blockDim.x + threadIdx.x;
    if (n >= N_NODES) return;
    const char* m2 = (const char*)msg2;
    const int st = off2[n << 3];
    const int en = off2[(n << 3) + 7];
    float addx = 0.f, addy = 0.f, curx = 0.f, cury = 0.f;
    int prev_r = -1;

#define MRG2(kk, ff) { \
    int r_ = ((kk) >> 3) & 7; \
    bool same_ = (r_ == prev_r); \
    addx += same_ ? 0.f : curx; \
    addy += same_ ? 0.f : cury; \
    curx = same_ ? fmaxf(curx, (ff).x) : (ff).x; \
    cury = same_ ? fmaxf(cury, (ff).y) : (ff).y; \
    prev_r = r_; }

    int p = st;
    for (; p + 1 < en; p += 2) {
        int k0 = packed2[p], k1 = packed2[p + 1];
        float2 f0 = *(const float2*)(m2 + k0);
        float2 f1 = *(const float2*)(m2 + k1);
        MRG2(k0, f0) MRG2(k1, f1)
    }
    if (p < en) {
        int k0 = packed2[p];
        float2 f0 = *(const float2*)(m2 + k0);
        MRG2(k0, f0)
    }
#undef MRG2

    out[(size_t)n * 2 + 0] = msg2[(size_t)n * 16 + 14] + addx + curx;
    out[(size_t)n * 2 + 1] = msg2[(size_t)n * 16 + 15] + addy + cury;
}

extern "C" void kernel_launch(void* const* d_in, const int* in_sizes, int n_in,
                              void* d_out, int out_size, void* d_ws, size_t ws_size,
                              hipStream_t stream)
{
    const float* x      = (const float*)d_in[0];
    const int*   ei     = (const int*)d_in[1];
    const int*   et     = (const int*)d_in[2];
    const float* W1     = (const float*)d_in[3];
    const float* root1  = (const float*)d_in[4];
    const float* bias1  = (const float*)d_in[5];
    const float* comp2  = (const float*)d_in[6];
    const float* basis2 = (const float*)d_in[7];
    const float* root2  = (const float*)d_in[8];
    const float* bias2  = (const float*)d_in[9];
    float* out = (float*)d_out;

    // workspace carve-up (~165 MB)
    char* ws = (char*)d_ws;
    size_t o = 0;
    auto carve = [&](size_t bytes) { char* p = ws + o; o += (bytes + 255) & ~(size_t)255; return p; };
    int*   deg2    = (int*)carve(sizeof(int) * NBINS);
    int*   off2    = (int*)carve(sizeof(int) * (NBINS + 1));
    int*   cursor2 = (int*)carve(sizeof(int) * (NBINS + 1));
    int*   sums    = (int*)carve(sizeof(int) * 1024);
    int*   packed1 = (int*)carve(sizeof(int) * N_EDGESV);
    int*   packed2 = (int*)carve(sizeof(int) * N_EDGESV);
    f16*   xh      = (f16*)carve(sizeof(f16) * (size_t)N_NODES * IN_CH);        // 25.6 MB
    f16*   wbt     = (f16*)carve(sizeof(f16) * 512 * 128);                      // 128 KB
    f16*   w2t     = (f16*)carve(sizeof(f16) * 16 * 64);                        //   2 KB
    f16*   dense1  = (f16*)carve(sizeof(f16) * (size_t)N_NODES * 512);          // 102.4 MB
    f16*   h16     = (f16*)carve(sizeof(f16) * (size_t)N_NODES * HID_CH);       // 12.8 MB
    float* msg2    = (float*)carve(sizeof(float) * (size_t)N_NODES * 16);       //  6.4 MB

    // ---- CSR build over (dst, rel) ----
    hipMemsetAsync(deg2, 0, sizeof(int) * NBINS, stream);
    hist_kernel<<<(N_EDGESV + 255) / 256, 256, 0, stream>>>(ei, et, deg2);
    scan1_kernel<<<NCHUNK2, 256, 0, stream>>>(deg2, off2, sums);
    scan2_kernel<<<1, 1024, 0, stream>>>(sums);
    scan3_kernel<<<(NBINS + 255) / 256, 256, 0, stream>>>(off2, sums, cursor2);
    scatter_kernel<<<(N_EDGESV + 255) / 256, 256, 0, stream>>>(ei, et, cursor2, packed1, packed2);

    // ---- fp16 staging + MFMA dense precompute ----
    xh_kernel<<<(N_NODES * IN_CH / 4 + 255) / 256, 256, 0, stream>>>(x, xh);
    wbuild_kernel<<<64, 256, 0, stream>>>(root1, W1, comp2, basis2, root2, wbt, w2t);
    gemm1_kernel<<<1024, 512, 0, stream>>>(xh, wbt, dense1);

    // ---- layer 1 aggregation ----
    agg1_kernel<<<2048, 256, 0, stream>>>(dense1, bias1, off2, packed1, h16);

    // ---- layer 2: MFMA messages + aggregation ----
    pre2_kernel<<<(NTILES + 3) / 4, 256, 0, stream>>>(h16, w2t, bias2, msg2);
    agg2_kernel<<<(N_NODES + 255) / 256, 256, 0, stream>>>(msg2, off2, packed2, out);
}